// Round 7
// baseline (492.039 us; speedup 1.0000x reference)
//
#include <hip/hip_runtime.h>

#define N_NODES 100000
#define N_EDGES 1600000
#define D 128

typedef unsigned short ushort_t;
struct ushort4_t { ushort_t x, y, z, w; };
typedef float vf2 __attribute__((ext_vector_type(2)));
typedef __attribute__((ext_vector_type(8))) short bf16x8;
typedef __attribute__((ext_vector_type(4))) float f32x4;

__device__ __forceinline__ ushort_t f2bf(float f) {
    unsigned u = __float_as_uint(f);
    unsigned r = (u + 0x7fffu + ((u >> 16) & 1u)) >> 16;   // RNE
    return (ushort_t)r;
}
__device__ __forceinline__ float bf2f(ushort_t b) {
    return __uint_as_float(((unsigned)b) << 16);
}

// ---------------- Kernel 1: LayerNorm + ReLU -> bf16 h ---------------------------
__global__ __launch_bounds__(256) void ln_relu_kernel(
    const float* __restrict__ x, const float* __restrict__ gamma,
    const float* __restrict__ beta, ushort_t* __restrict__ hb)
{
    int wave   = threadIdx.x >> 6;
    int half   = (threadIdx.x >> 5) & 1;
    int lane32 = threadIdx.x & 31;
    int row = blockIdx.x * 8 + wave * 2 + half;
    float4 v = ((const float4*)(x + (size_t)row * D))[lane32];
    float s  = (v.x + v.y) + (v.z + v.w);
    float sq = (v.x * v.x + v.y * v.y) + (v.z * v.z + v.w * v.w);
#pragma unroll
    for (int m = 16; m >= 1; m >>= 1) {        // stays within the 32-lane half
        s  += __shfl_xor(s, m);
        sq += __shfl_xor(sq, m);
    }
    float mu   = s * (1.0f / D);
    float var  = sq * (1.0f / D) - mu * mu;
    float rstd = rsqrtf(var + 1e-5f);
    float4 g = ((const float4*)gamma)[lane32];
    float4 b = ((const float4*)beta)[lane32];
    ushort4_t o;
    o.x = f2bf(fmaxf(fmaf((v.x - mu) * rstd, g.x, b.x), 0.0f));
    o.y = f2bf(fmaxf(fmaf((v.y - mu) * rstd, g.y, b.y), 0.0f));
    o.z = f2bf(fmaxf(fmaf((v.z - mu) * rstd, g.z, b.z), 0.0f));
    o.w = f2bf(fmaxf(fmaf((v.w - mu) * rstd, g.w, b.w), 0.0f));
    *(ushort4_t*)(hb + (size_t)row * D + lane32 * 4) = o;
}

// ---------------- Kernel 1b: detect edge dtype (int64 vs int32 view) ------------
__global__ void detect_kernel(const int* __restrict__ e, int* __restrict__ flag)
{
    int z = 1;
    for (int i = 1; i < 128; i += 2) z &= (e[i] == 0) ? 1 : 0;
    *flag = z;  // 1 => int64 layout
}

// ---------------- Kernel 1c: W -> bf16 (row-major, same layout) ------------------
__global__ __launch_bounds__(256) void wbf_kernel(
    const float* __restrict__ W, ushort_t* __restrict__ wbf)
{
    int i = (blockIdx.x * 256 + threadIdx.x) * 4;   // 16 blocks cover 16384
    float4 w = *(const float4*)(W + i);
    ushort4_t o;
    o.x = f2bf(w.x); o.y = f2bf(w.y); o.z = f2bf(w.z); o.w = f2bf(w.w);
    *(ushort4_t*)(wbf + i) = o;
}

// ---------------- Kernel 2: build per-dst linked chains --------------------------
// chain[e] = src | (next << 32). Plain stores (chain re-read by segsum).
__global__ __launch_bounds__(256) void chain_build_kernel(
    const void* __restrict__ e_raw, const int* __restrict__ flag,
    long long* __restrict__ chain, int* __restrict__ head)
{
    int e = blockIdx.x * 256 + threadIdx.x;   // exactly N_EDGES threads
    int s, d;
    if (*flag) {
        s = (int)((const long long*)e_raw)[e];
        d = (int)((const long long*)e_raw)[N_EDGES + e];
    } else {
        s = ((const int*)e_raw)[e];
        d = ((const int*)e_raw)[N_EDGES + e];
    }
    int old = atomicExch(&head[d], e);
    chain[e] = (long long)(unsigned int)s | ((long long)old << 32);
}

// ---------------- Kernel 3: segment sum — lane-parallel chase --------------------
// Wave owns 32 nodes. Lanes 0..31 each chase one node's chain (vector 8B loads,
// 32 independent misses per instruction). Each round, lane j's src is broadcast
// via readlane and all 64 lanes gather that row coalesced (dword/lane) into
// acc[j] (2 VGPRs per node). Dead chains cost one scalar branch only.
__global__ __launch_bounds__(256) void chain_segsum_kernel(
    const ushort_t* __restrict__ hb, const int* __restrict__ head,
    const long long* __restrict__ chain, float* __restrict__ aggr)
{
    const int wid = blockIdx.x * 4 + (threadIdx.x >> 6);
    if (wid >= N_NODES / 32) return;           // 3125 waves exactly
    const int lane = threadIdx.x & 63;
    const int base = wid * 32;

    int cur = (lane < 32) ? head[base + lane] : -1;

    float accx[32], accy[32];
#pragma unroll
    for (int j = 0; j < 32; ++j) { accx[j] = 0.0f; accy[j] = 0.0f; }

    const unsigned* hrow = (const unsigned*)hb;   // 64 dwords per node row

    while (__ballot(cur != -1)) {
        int srcv = -1;
        if (cur != -1) {
            long long c = chain[cur];             // per-lane random 8B load
            srcv = (int)(unsigned int)c;
            cur  = (int)(c >> 32);
        }
#pragma unroll
        for (int j = 0; j < 32; ++j) {
            int s = __builtin_amdgcn_readlane(srcv, j);   // wave-uniform
            if (s != -1) {                                 // scalar branch
                unsigned p = hrow[(size_t)s * 64 + lane];  // coalesced 256B row
                accx[j] += bf2f((ushort_t)(p & 0xffffu));
                accy[j] += bf2f((ushort_t)(p >> 16));
            }
        }
    }

#pragma unroll
    for (int j = 0; j < 32; ++j) {
        vf2 o = {accx[j], accy[j]};
        __builtin_nontemporal_store(o, (vf2*)(aggr + (size_t)(base + j) * D + lane * 2));
    }
}

// ---------------- Kernel 4: out = ((1+eps)h + aggr) @ W^T + b + x  (MFMA) --------
// Block = 256 (4 waves); wave owns 16 rows x 128 cols = 8 tiles of 16x16, K=128
// in 4 steps of 32. Fragments loaded global->reg directly; no LDS, no barriers.
// B now loads pre-converted bf16 W (no inner-loop cvt).
// C/D: col = lane&15, row = (lane>>4)*4 + reg   [m89]
// aggr aliases out: each wave reads only its own 16 rows, writes them after.
__global__ __launch_bounds__(256) void gemm_mfma_kernel(
    const ushort_t* __restrict__ hb, const float* __restrict__ aggr,
    const float* __restrict__ x, const ushort_t* __restrict__ wbf,
    const float* __restrict__ bias, const float* __restrict__ eps_p,
    float* __restrict__ out)
{
    const int wv   = threadIdx.x >> 6;
    const int lane = threadIdx.x & 63;
    const int l16  = lane & 15;
    const int kg   = lane >> 4;                 // 0..3
    const int row  = blockIdx.x * 64 + wv * 16 + l16;
    const int rowc = row < N_NODES ? row : N_NODES - 1;
    const float ep1 = 1.0f + eps_p[0];

    f32x4 acc[8];
#pragma unroll
    for (int nt = 0; nt < 8; ++nt) acc[nt] = (f32x4){0.f, 0.f, 0.f, 0.f};

#pragma unroll
    for (int ks = 0; ks < 4; ++ks) {
        const int k0 = ks * 32 + kg * 8;
        // ---- A fragment: t = bf16(ep1*h + aggr), 8 elems of row `rowc` ----
        const ushort_t* hp = hb   + (size_t)rowc * D + k0;
        const float*    ap = aggr + (size_t)rowc * D + k0;
        ushort4_t h0 = *(const ushort4_t*)(hp);
        ushort4_t h1 = *(const ushort4_t*)(hp + 4);
        float4 a0 = *(const float4*)(ap);
        float4 a1 = *(const float4*)(ap + 4);
        bf16x8 af;
        af[0] = (short)f2bf(fmaf(ep1, bf2f(h0.x), a0.x));
        af[1] = (short)f2bf(fmaf(ep1, bf2f(h0.y), a0.y));
        af[2] = (short)f2bf(fmaf(ep1, bf2f(h0.z), a0.z));
        af[3] = (short)f2bf(fmaf(ep1, bf2f(h0.w), a0.w));
        af[4] = (short)f2bf(fmaf(ep1, bf2f(h1.x), a1.x));
        af[5] = (short)f2bf(fmaf(ep1, bf2f(h1.y), a1.y));
        af[6] = (short)f2bf(fmaf(ep1, bf2f(h1.z), a1.z));
        af[7] = (short)f2bf(fmaf(ep1, bf2f(h1.w), a1.w));

#pragma unroll
        for (int nt = 0; nt < 8; ++nt) {
            bf16x8 bf = *(const bf16x8*)(wbf + (size_t)(nt * 16 + l16) * D + k0);
            acc[nt] = __builtin_amdgcn_mfma_f32_16x16x32_bf16(af, bf, acc[nt], 0, 0, 0);
        }
    }

    // ---- epilogue: + bias + residual x ----
#pragma unroll
    for (int nt = 0; nt < 8; ++nt) {
        int col = nt * 16 + l16;
        float bv = bias[col];
#pragma unroll
        for (int r = 0; r < 4; ++r) {
            int orow = blockIdx.x * 64 + wv * 16 + kg * 4 + r;
            if (orow < N_NODES)
                out[(size_t)orow * D + col] = acc[nt][r] + bv + x[(size_t)orow * D + col];
        }
    }
}

extern "C" void kernel_launch(void* const* d_in, const int* in_sizes, int n_in,
                              void* d_out, int out_size, void* d_ws, size_t ws_size,
                              hipStream_t stream)
{
    const float* x     = (const float*)d_in[0];
    const void*  ei    = d_in[1];
    const float* gamma = (const float*)d_in[2];
    const float* beta  = (const float*)d_in[3];
    const float* W     = (const float*)d_in[4];
    const float* bias  = (const float*)d_in[5];
    const float* eps_p = (const float*)d_in[6];
    float* out = (float*)d_out;

    char* ws = (char*)d_ws;
    size_t off = 0;
    ushort_t*  hb    = (ushort_t*)(ws + off);  off += (size_t)N_NODES * D * 2;   // 25.6 MB
    long long* chain = (long long*)(ws + off); off += (size_t)N_EDGES * 8;       // 12.8 MB
    int*       head  = (int*)(ws + off);       off += (size_t)N_NODES * 4;       //  0.4 MB
    ushort_t*  wbf   = (ushort_t*)(ws + off);  off += (size_t)D * D * 2;         //  32 KB
    int*       flag  = (int*)(ws + off);       off += 4;

    detect_kernel<<<1, 1, 0, stream>>>((const int*)ei, flag);
    (void)hipMemsetAsync(head, 0xFF, (size_t)N_NODES * 4, stream);               // head = -1
    chain_build_kernel<<<N_EDGES / 256, 256, 0, stream>>>(ei, flag, chain, head);
    ln_relu_kernel<<<N_NODES / 8, 256, 0, stream>>>(x, gamma, beta, hb);
    wbf_kernel<<<16, 256, 0, stream>>>(W, wbf);
    chain_segsum_kernel<<<(N_NODES / 32 + 3) / 4, 256, 0, stream>>>(hb, head, chain, out);
    gemm_mfma_kernel<<<(N_NODES + 63) / 64, 256, 0, stream>>>(hb, out, x, wbf, bias, eps_p, out);
}

// Round 8
// 342.627 us; speedup vs baseline: 1.4361x; 1.4361x over previous
//
#include <hip/hip_runtime.h>

#define N_NODES 100000
#define N_EDGES 1600000
#define D 128

typedef unsigned short ushort_t;
struct ushort4_t { ushort_t x, y, z, w; };
typedef float vf2 __attribute__((ext_vector_type(2)));
typedef __attribute__((ext_vector_type(8))) short bf16x8;
typedef __attribute__((ext_vector_type(4))) float f32x4;

__device__ __forceinline__ ushort_t f2bf(float f) {
    unsigned u = __float_as_uint(f);
    unsigned r = (u + 0x7fffu + ((u >> 16) & 1u)) >> 16;   // RNE
    return (ushort_t)r;
}
__device__ __forceinline__ float bf2f(ushort_t b) {
    return __uint_as_float(((unsigned)b) << 16);
}

// ---------------- Kernel 1: LayerNorm + ReLU -> bf16 h ---------------------------
__global__ __launch_bounds__(256) void ln_relu_kernel(
    const float* __restrict__ x, const float* __restrict__ gamma,
    const float* __restrict__ beta, ushort_t* __restrict__ hb)
{
    int wave   = threadIdx.x >> 6;
    int half   = (threadIdx.x >> 5) & 1;
    int lane32 = threadIdx.x & 31;
    int row = blockIdx.x * 8 + wave * 2 + half;
    float4 v = ((const float4*)(x + (size_t)row * D))[lane32];
    float s  = (v.x + v.y) + (v.z + v.w);
    float sq = (v.x * v.x + v.y * v.y) + (v.z * v.z + v.w * v.w);
#pragma unroll
    for (int m = 16; m >= 1; m >>= 1) {        // stays within the 32-lane half
        s  += __shfl_xor(s, m);
        sq += __shfl_xor(sq, m);
    }
    float mu   = s * (1.0f / D);
    float var  = sq * (1.0f / D) - mu * mu;
    float rstd = rsqrtf(var + 1e-5f);
    float4 g = ((const float4*)gamma)[lane32];
    float4 b = ((const float4*)beta)[lane32];
    ushort4_t o;
    o.x = f2bf(fmaxf(fmaf((v.x - mu) * rstd, g.x, b.x), 0.0f));
    o.y = f2bf(fmaxf(fmaf((v.y - mu) * rstd, g.y, b.y), 0.0f));
    o.z = f2bf(fmaxf(fmaf((v.z - mu) * rstd, g.z, b.z), 0.0f));
    o.w = f2bf(fmaxf(fmaf((v.w - mu) * rstd, g.w, b.w), 0.0f));
    *(ushort4_t*)(hb + (size_t)row * D + lane32 * 4) = o;
}

// ---------------- Kernel 1b: detect edge dtype (int64 vs int32 view) ------------
__global__ void detect_kernel(const int* __restrict__ e, int* __restrict__ flag)
{
    int z = 1;
    for (int i = 1; i < 128; i += 2) z &= (e[i] == 0) ? 1 : 0;
    *flag = z;  // 1 => int64 layout
}

// ---------------- Kernel 1c: W -> bf16 (row-major, same layout) ------------------
__global__ __launch_bounds__(256) void wbf_kernel(
    const float* __restrict__ W, ushort_t* __restrict__ wbf)
{
    int i = (blockIdx.x * 256 + threadIdx.x) * 4;   // 16 blocks cover 16384
    float4 w = *(const float4*)(W + i);
    ushort4_t o;
    o.x = f2bf(w.x); o.y = f2bf(w.y); o.z = f2bf(w.z); o.w = f2bf(w.w);
    *(ushort4_t*)(wbf + i) = o;
}

// ---------------- Kernel 2: build per-dst linked chains --------------------------
// chain[e] = src | (next << 32). Plain chain stores (re-read by segsum);
// NT loads on the once-streamed edge array.
__global__ __launch_bounds__(256) void chain_build_kernel(
    const void* __restrict__ e_raw, const int* __restrict__ flag,
    long long* __restrict__ chain, int* __restrict__ head)
{
    int e = blockIdx.x * 256 + threadIdx.x;   // exactly N_EDGES threads
    int s, d;
    if (*flag) {
        s = (int)__builtin_nontemporal_load(&((const long long*)e_raw)[e]);
        d = (int)__builtin_nontemporal_load(&((const long long*)e_raw)[N_EDGES + e]);
    } else {
        s = __builtin_nontemporal_load(&((const int*)e_raw)[e]);
        d = __builtin_nontemporal_load(&((const int*)e_raw)[N_EDGES + e]);
    }
    int old = atomicExch(&head[d], e);
    chain[e] = (long long)(unsigned int)s | ((long long)old << 32);
    if (e == 0) chain[N_EDGES] = -1LL;        // sentinel: {src=-1, next=-1}
}

// ---------------- Kernel 3: segment sum via chain walk — 8 chains per wave -------
// Branchless sentinel chain loads give 8-deep MLP on the dependent chase.
// (Round-6 structure: measured 174 us, 61% occupancy.)
__global__ __launch_bounds__(256) void chain_segsum_kernel(
    const ushort_t* __restrict__ hb, const int* __restrict__ head,
    const long long* __restrict__ chain, float* __restrict__ aggr)
{
    int wid  = blockIdx.x * 4 + (threadIdx.x >> 6);
    int lane = threadIdx.x & 63;
    int base = wid * 8;

    int e[8];
    float ax[8], ay[8];
#pragma unroll
    for (int i = 0; i < 8; ++i) {
        e[i] = __builtin_amdgcn_readfirstlane(head[base + i]);
        ax[i] = 0.0f; ay[i] = 0.0f;
    }

    for (;;) {
        bool any = false;
#pragma unroll
        for (int i = 0; i < 8; ++i) any = any || (e[i] != -1);
        if (!any) break;

        long long c[8];
#pragma unroll
        for (int i = 0; i < 8; ++i) {
            int idx = (e[i] == -1) ? N_EDGES : e[i];
            c[i] = chain[idx];                 // 8 independent loads in flight
        }
#pragma unroll
        for (int i = 0; i < 8; ++i) {
            int s = (int)(unsigned int)(c[i] & 0xffffffffLL);
            e[i] = __builtin_amdgcn_readfirstlane((int)(c[i] >> 32));
            if (s != -1) {                     // wave-uniform branch
                unsigned p = *(const unsigned*)(hb + (size_t)s * D + lane * 2);
                ax[i] += bf2f((ushort_t)(p & 0xffffu));
                ay[i] += bf2f((ushort_t)(p >> 16));
            }
        }
    }

#pragma unroll
    for (int i = 0; i < 8; ++i) {
        vf2 o = {ax[i], ay[i]};
        __builtin_nontemporal_store(o, (vf2*)(aggr + (size_t)(base + i) * D + lane * 2));
    }
}

// ---------------- Kernel 4: out = ((1+eps)h + aggr) @ W^T + b + x  (MFMA) --------
// Block = 256 (4 waves); wave owns 16 rows x 128 cols = 8 tiles of 16x16, K=128
// in 4 steps of 32. Fragments global->reg; no LDS, no barriers. B = precomputed
// bf16 W. C/D: col = lane&15, row = (lane>>4)*4 + reg  [m89].
// aggr aliases out: each wave reads only its own 16 rows, writes them after.
__global__ __launch_bounds__(256) void gemm_mfma_kernel(
    const ushort_t* __restrict__ hb, const float* __restrict__ aggr,
    const float* __restrict__ x, const ushort_t* __restrict__ wbf,
    const float* __restrict__ bias, const float* __restrict__ eps_p,
    float* __restrict__ out)
{
    const int wv   = threadIdx.x >> 6;
    const int lane = threadIdx.x & 63;
    const int l16  = lane & 15;
    const int kg   = lane >> 4;                 // 0..3
    const int row  = blockIdx.x * 64 + wv * 16 + l16;
    const int rowc = row < N_NODES ? row : N_NODES - 1;
    const float ep1 = 1.0f + eps_p[0];

    f32x4 acc[8];
#pragma unroll
    for (int nt = 0; nt < 8; ++nt) acc[nt] = (f32x4){0.f, 0.f, 0.f, 0.f};

#pragma unroll
    for (int ks = 0; ks < 4; ++ks) {
        const int k0 = ks * 32 + kg * 8;
        // ---- A fragment: t = bf16(ep1*h + aggr), 8 elems of row `rowc` ----
        const ushort_t* hp = hb   + (size_t)rowc * D + k0;
        const float*    ap = aggr + (size_t)rowc * D + k0;
        ushort4_t h0 = *(const ushort4_t*)(hp);
        ushort4_t h1 = *(const ushort4_t*)(hp + 4);
        float4 a0 = *(const float4*)(ap);
        float4 a1 = *(const float4*)(ap + 4);
        bf16x8 af;
        af[0] = (short)f2bf(fmaf(ep1, bf2f(h0.x), a0.x));
        af[1] = (short)f2bf(fmaf(ep1, bf2f(h0.y), a0.y));
        af[2] = (short)f2bf(fmaf(ep1, bf2f(h0.z), a0.z));
        af[3] = (short)f2bf(fmaf(ep1, bf2f(h0.w), a0.w));
        af[4] = (short)f2bf(fmaf(ep1, bf2f(h1.x), a1.x));
        af[5] = (short)f2bf(fmaf(ep1, bf2f(h1.y), a1.y));
        af[6] = (short)f2bf(fmaf(ep1, bf2f(h1.z), a1.z));
        af[7] = (short)f2bf(fmaf(ep1, bf2f(h1.w), a1.w));

#pragma unroll
        for (int nt = 0; nt < 8; ++nt) {
            bf16x8 bf = *(const bf16x8*)(wbf + (size_t)(nt * 16 + l16) * D + k0);
            acc[nt] = __builtin_amdgcn_mfma_f32_16x16x32_bf16(af, bf, acc[nt], 0, 0, 0);
        }
    }

    // ---- epilogue: + bias + residual x (NT on streamed x/out) ----
#pragma unroll
    for (int nt = 0; nt < 8; ++nt) {
        int col = nt * 16 + l16;
        float bv = bias[col];
#pragma unroll
        for (int r = 0; r < 4; ++r) {
            int orow = blockIdx.x * 64 + wv * 16 + kg * 4 + r;
            if (orow < N_NODES) {
                float xv = __builtin_nontemporal_load(&x[(size_t)orow * D + col]);
                __builtin_nontemporal_store(acc[nt][r] + bv + xv,
                                            &out[(size_t)orow * D + col]);
            }
        }
    }
}

extern "C" void kernel_launch(void* const* d_in, const int* in_sizes, int n_in,
                              void* d_out, int out_size, void* d_ws, size_t ws_size,
                              hipStream_t stream)
{
    const float* x     = (const float*)d_in[0];
    const void*  ei    = d_in[1];
    const float* gamma = (const float*)d_in[2];
    const float* beta  = (const float*)d_in[3];
    const float* W     = (const float*)d_in[4];
    const float* bias  = (const float*)d_in[5];
    const float* eps_p = (const float*)d_in[6];
    float* out = (float*)d_out;

    char* ws = (char*)d_ws;
    size_t off = 0;
    ushort_t*  hb    = (ushort_t*)(ws + off);  off += (size_t)N_NODES * D * 2;   // 25.6 MB
    long long* chain = (long long*)(ws + off); off += (size_t)(N_EDGES + 1) * 8; // 12.8 MB
    int*       head  = (int*)(ws + off);       off += (size_t)N_NODES * 4;       //  0.4 MB
    ushort_t*  wbf   = (ushort_t*)(ws + off);  off += (size_t)D * D * 2;         //  32 KB
    int*       flag  = (int*)(ws + off);       off += 4;

    detect_kernel<<<1, 1, 0, stream>>>((const int*)ei, flag);
    (void)hipMemsetAsync(head, 0xFF, (size_t)N_NODES * 4, stream);               // head = -1
    chain_build_kernel<<<N_EDGES / 256, 256, 0, stream>>>(ei, flag, chain, head);
    ln_relu_kernel<<<N_NODES / 8, 256, 0, stream>>>(x, gamma, beta, hb);
    wbf_kernel<<<16, 256, 0, stream>>>(W, wbf);
    chain_segsum_kernel<<<N_NODES / 32, 256, 0, stream>>>(hb, head, chain, out);
    gemm_mfma_kernel<<<(N_NODES + 63) / 64, 256, 0, stream>>>(hb, out, x, wbf, bias, eps_p, out);
}